// Round 3
// baseline (3412.081 us; speedup 1.0000x reference)
//
#include <hip/hip_runtime.h>

namespace {
constexpr int B = 16, C = 256, N = 16384, K = 64;
constexpr float TEMP = 20.0f, EPS = 1e-6f;
}

// Fused EM step. Block = (256 n's of one batch). Thread = (n-pair, k-half):
//   q = tid>>1 in [0,128): n's {n0+q, n0+q+128};  kh = tid&1: k in [kh*32, kh*32+32)
// Phase 1: scores -> softmax (TEMP unless FINAL). FINAL: write fp32 out, done.
// Phase 2: z-tile into LDS (reusing the m buffer), S column sums (atomic),
//          partial m' = sum_n x*z with c-mapping {q, q+128}, atomicAdd into mt.
template <bool FINAL>
__global__ __launch_bounds__(256) void kstep_kernel(
    const float* __restrict__ x,   // [B][C][N] fp32
    const float* __restrict__ m,   // [B][C][K] fp32
    float* __restrict__ mt,        // [B][C][K] accum (pre-zeroed)
    float* __restrict__ S,         // [B][K] accum (pre-zeroed)
    float* __restrict__ out) {     // [B][N][K] fp32
  __shared__ float sm[C * K];  // 64 KB: phase1 = m[b], phase2 = z-tile [256][K]
  const int tid = threadIdx.x;
  const int b = blockIdx.y;
  const int n0 = blockIdx.x * 256;
  const int kh = tid & 1;
  const int q = tid >> 1;

  {  // stage m[b] -> LDS (coalesced float4)
    const float4* src = (const float4*)(m + (size_t)b * C * K);
    float4* dst = (float4*)sm;
#pragma unroll
    for (int i = 0; i < 16; ++i) dst[tid + 256 * i] = src[tid + 256 * i];
  }
  __syncthreads();

  // ---- phase 1: scores ----
  float a0[32], a1[32];
#pragma unroll
  for (int i = 0; i < 32; ++i) { a0[i] = 0.f; a1[i] = 0.f; }

  const float* xb = x + (size_t)b * C * N + n0 + q;
  const float4* sm4 = (const float4*)sm;
  for (int c = 0; c < C; ++c) {
    float x0 = xb[(size_t)c * N];        // coalesced across lanes
    float x1 = xb[(size_t)c * N + 128];
#pragma unroll
    for (int j = 0; j < 8; ++j) {
      float4 mv = sm4[c * 16 + kh * 8 + j];  // 2 distinct addrs/wave -> broadcast
      a0[4 * j + 0] += x0 * mv.x; a0[4 * j + 1] += x0 * mv.y;
      a0[4 * j + 2] += x0 * mv.z; a0[4 * j + 3] += x0 * mv.w;
      a1[4 * j + 0] += x1 * mv.x; a1[4 * j + 1] += x1 * mv.y;
      a1[4 * j + 2] += x1 * mv.z; a1[4 * j + 3] += x1 * mv.w;
    }
  }

  // ---- softmax over k (pairwise across tid^1 which holds the other k-half) ----
  const float sc = FINAL ? 1.0f : TEMP;  // final einsum has NO temperature
  float mx0 = -1e30f, mx1 = -1e30f;
#pragma unroll
  for (int i = 0; i < 32; ++i) {
    a0[i] *= sc; a1[i] *= sc;
    mx0 = fmaxf(mx0, a0[i]); mx1 = fmaxf(mx1, a1[i]);
  }
  mx0 = fmaxf(mx0, __shfl_xor(mx0, 1));
  mx1 = fmaxf(mx1, __shfl_xor(mx1, 1));
  float s0 = 0.f, s1 = 0.f;
#pragma unroll
  for (int i = 0; i < 32; ++i) {
    a0[i] = __expf(a0[i] - mx0); s0 += a0[i];
    a1[i] = __expf(a1[i] - mx1); s1 += a1[i];
  }
  s0 += __shfl_xor(s0, 1);
  s1 += __shfl_xor(s1, 1);
  const float i0 = 1.0f / s0, i1 = 1.0f / s1;
#pragma unroll
  for (int i = 0; i < 32; ++i) { a0[i] *= i0; a1[i] *= i1; }

  if (FINAL) {
    float4* o0 = (float4*)(out + ((size_t)b * N + n0 + q) * K + kh * 32);
    float4* o1 = (float4*)(out + ((size_t)b * N + n0 + q + 128) * K + kh * 32);
#pragma unroll
    for (int g = 0; g < 8; ++g) {
      o0[g] = make_float4(a0[4 * g], a0[4 * g + 1], a0[4 * g + 2], a0[4 * g + 3]);
      o1[g] = make_float4(a1[4 * g], a1[4 * g + 1], a1[4 * g + 2], a1[4 * g + 3]);
    }
    return;
  }

  // ---- phase 2 ----
  __syncthreads();  // everyone done reading sm as m
  {                 // write z-tile [nloc][k] into sm
    float4* z0 = (float4*)&sm[q * K + kh * 32];
    float4* z1 = (float4*)&sm[(q + 128) * K + kh * 32];
#pragma unroll
    for (int g = 0; g < 8; ++g) {
      z0[g] = make_float4(a0[4 * g], a0[4 * g + 1], a0[4 * g + 2], a0[4 * g + 3]);
      z1[g] = make_float4(a1[4 * g], a1[4 * g + 1], a1[4 * g + 2], a1[4 * g + 3]);
    }
  }
  __syncthreads();

  {  // S[b,k] += sum over this block's n of z; thread = (k, n-quarter)
    const int k = tid & 63, qt = tid >> 6;
    float s = 0.f;
#pragma unroll
    for (int nn = 0; nn < 64; ++nn) s += sm[(qt * 64 + nn) * K + k];
    atomicAdd(&S[b * K + k], s);
  }

  // partial m'[c,k] = sum_{nn} x[c, n0+nn] * z[nn, k]; c in {q, q+128}
  float b0[32], b1[32];
#pragma unroll
  for (int i = 0; i < 32; ++i) { b0[i] = 0.f; b1[i] = 0.f; }

  const float4* xr0 = (const float4*)(x + ((size_t)b * C + q) * N + n0);
  const float4* xr1 = (const float4*)(x + ((size_t)b * C + q + 128) * N + n0);
  for (int t = 0; t < 64; ++t) {  // 4 n's per iter
    float4 w0 = xr0[t], w1 = xr1[t];
#pragma unroll
    for (int d = 0; d < 4; ++d) {
      const int nn = t * 4 + d;
      const float xv0 = d == 0 ? w0.x : d == 1 ? w0.y : d == 2 ? w0.z : w0.w;
      const float xv1 = d == 0 ? w1.x : d == 1 ? w1.y : d == 2 ? w1.z : w1.w;
#pragma unroll
      for (int j = 0; j < 8; ++j) {
        float4 zv = sm4[nn * 16 + kh * 8 + j];  // broadcast
        b0[4 * j + 0] += xv0 * zv.x; b0[4 * j + 1] += xv0 * zv.y;
        b0[4 * j + 2] += xv0 * zv.z; b0[4 * j + 3] += xv0 * zv.w;
        b1[4 * j + 0] += xv1 * zv.x; b1[4 * j + 1] += xv1 * zv.y;
        b1[4 * j + 2] += xv1 * zv.z; b1[4 * j + 3] += xv1 * zv.w;
      }
    }
  }

  float* mt0 = mt + ((size_t)b * C + q) * K + kh * 32;
  float* mt1 = mt + ((size_t)b * C + q + 128) * K + kh * 32;
#pragma unroll
  for (int i = 0; i < 32; ++i) {
    atomicAdd(&mt0[i], b0[i]);
    atomicAdd(&mt1[i], b1[i]);
  }
}

// m[b,c,k] = l2norm_c( mt[b,:,k] * l1scale[k] );  l1scale = 1/(EPS + S[b,k])
__global__ __launch_bounds__(64) void kl2_kernel(const float* __restrict__ mt,
                                                 const float* __restrict__ S,
                                                 float* __restrict__ m) {
  const int k = blockIdx.x, b = blockIdx.y, lane = threadIdx.x;
  const float s = 1.0f / (EPS + S[b * K + k]);
  float v[4];
  float ss = 0.f;
#pragma unroll
  for (int i = 0; i < 4; ++i) {
    v[i] = mt[((size_t)b * C + lane + 64 * i) * K + k] * s;
    ss += v[i] * v[i];
  }
#pragma unroll
  for (int off = 32; off >= 1; off >>= 1) ss += __shfl_xor(ss, off);
  const float inv = 1.0f / (EPS + sqrtf(ss));
#pragma unroll
  for (int i = 0; i < 4; ++i)
    m[((size_t)b * C + lane + 64 * i) * K + k] = v[i] * inv;
}

// init: m[b,c,k] = mu[c,k] (fp32 broadcast over b)
__global__ __launch_bounds__(256) void kinit_kernel(
    const float* __restrict__ mu, float* __restrict__ m) {
  const int idx = blockIdx.x * 256 + threadIdx.x;
  m[idx] = mu[idx & (C * K - 1)];
}

__global__ __launch_bounds__(256) void kzero_kernel(float* __restrict__ p, int ntot) {
  const int i = blockIdx.x * 256 + threadIdx.x;
  if (i < ntot) p[i] = 0.f;
}

extern "C" void kernel_launch(void* const* d_in, const int* in_sizes, int n_in,
                              void* d_out, int out_size, void* d_ws,
                              size_t ws_size, hipStream_t stream) {
  const float* x = (const float*)d_in[0];   // fp32 [B][C][N]
  const float* mu = (const float*)d_in[1];  // fp32 [1][C][K]
  float* out = (float*)d_out;               // fp32 [B][N][K]

  // ws layout (fp32): m[B*C*K] | mt[B*C*K] | S[B*K]  (~2.01 MB total)
  float* m = (float*)d_ws;
  float* mt = m + (size_t)B * C * K;
  float* S = mt + (size_t)B * C * K;
  const int nz = B * C * K + B * K;  // mt + S contiguous

  kinit_kernel<<<B * C * K / 256, 256, 0, stream>>>(mu, m);
  for (int step = 0; step < 3; ++step) {
    kzero_kernel<<<(nz + 255) / 256, 256, 0, stream>>>(mt, nz);
    kstep_kernel<false><<<dim3(N / 256, B), 256, 0, stream>>>(x, m, mt, S, nullptr);
    kl2_kernel<<<dim3(K, B), 64, 0, stream>>>(mt, S, m);
  }
  kstep_kernel<true><<<dim3(N / 256, B), 256, 0, stream>>>(x, m, nullptr, nullptr, out);
}

// Round 4
// 3393.320 us; speedup vs baseline: 1.0055x; 1.0055x over previous
//
#include <hip/hip_runtime.h>

namespace {
constexpr int B = 16, C = 256, N = 16384, K = 64;
constexpr float TEMP = 20.0f, EPS = 1e-6f;
}

// Fused EM step. Block = (256 n's of one batch). Thread = (n-pair, k-half):
//   q = tid>>1 in [0,128): n's {n0+q, n0+q+128};  kh = tid&1: k in [kh*32, kh*32+32)
// Phase 1: scores -> softmax (TEMP unless FINAL). FINAL: write fp32 out, done.
// Phase 2: z-tile into LDS (reusing the m buffer), S column sums (atomic),
//          partial m' = sum_n x*z with c-mapping {q, q+128}, atomicAdd into mt.
//
// __launch_bounds__(256, 2): LDS=64KB caps us at 2 blocks/CU (= 2 waves/EU)
// anyway; without this the allocator targets 4 waves/EU -> 112 VGPRs -> ~2KB
// of scratch spill per thread (round-3 counters: WRITE_SIZE 525MB vs 67MB
// legitimate). Giving it the 256-VGPR budget eliminates all spills.
template <bool FINAL>
__global__ __launch_bounds__(256, 2) void kstep_kernel(
    const float* __restrict__ x,   // [B][C][N] fp32
    const float* __restrict__ m,   // [B][C][K] fp32
    float* __restrict__ mt,        // [B][C][K] accum (pre-zeroed)
    float* __restrict__ S,         // [B][K] accum (pre-zeroed)
    float* __restrict__ out) {     // [B][N][K] fp32
  __shared__ float sm[C * K];  // 64 KB: phase1 = m[b], phase2 = z-tile [256][K]
  const int tid = threadIdx.x;
  const int b = blockIdx.y;
  const int n0 = blockIdx.x * 256;
  const int kh = tid & 1;
  const int q = tid >> 1;

  {  // stage m[b] -> LDS (coalesced float4)
    const float4* src = (const float4*)(m + (size_t)b * C * K);
    float4* dst = (float4*)sm;
#pragma unroll
    for (int i = 0; i < 16; ++i) dst[tid + 256 * i] = src[tid + 256 * i];
  }
  __syncthreads();

  // ---- phase 1: scores ----
  float a0[32], a1[32];
#pragma unroll
  for (int i = 0; i < 32; ++i) { a0[i] = 0.f; a1[i] = 0.f; }

  const float* xb = x + (size_t)b * C * N + n0 + q;
  const float4* sm4 = (const float4*)sm;
  for (int c = 0; c < C; ++c) {
    float x0 = xb[(size_t)c * N];        // coalesced across lanes
    float x1 = xb[(size_t)c * N + 128];
#pragma unroll
    for (int j = 0; j < 8; ++j) {
      float4 mv = sm4[c * 16 + kh * 8 + j];  // 2 distinct addrs/wave -> broadcast
      a0[4 * j + 0] += x0 * mv.x; a0[4 * j + 1] += x0 * mv.y;
      a0[4 * j + 2] += x0 * mv.z; a0[4 * j + 3] += x0 * mv.w;
      a1[4 * j + 0] += x1 * mv.x; a1[4 * j + 1] += x1 * mv.y;
      a1[4 * j + 2] += x1 * mv.z; a1[4 * j + 3] += x1 * mv.w;
    }
  }

  // ---- softmax over k (pairwise across tid^1 which holds the other k-half) ----
  const float sc = FINAL ? 1.0f : TEMP;  // final einsum has NO temperature
  float mx0 = -1e30f, mx1 = -1e30f;
#pragma unroll
  for (int i = 0; i < 32; ++i) {
    a0[i] *= sc; a1[i] *= sc;
    mx0 = fmaxf(mx0, a0[i]); mx1 = fmaxf(mx1, a1[i]);
  }
  mx0 = fmaxf(mx0, __shfl_xor(mx0, 1));
  mx1 = fmaxf(mx1, __shfl_xor(mx1, 1));
  float s0 = 0.f, s1 = 0.f;
#pragma unroll
  for (int i = 0; i < 32; ++i) {
    a0[i] = __expf(a0[i] - mx0); s0 += a0[i];
    a1[i] = __expf(a1[i] - mx1); s1 += a1[i];
  }
  s0 += __shfl_xor(s0, 1);
  s1 += __shfl_xor(s1, 1);
  const float i0 = 1.0f / s0, i1 = 1.0f / s1;
#pragma unroll
  for (int i = 0; i < 32; ++i) { a0[i] *= i0; a1[i] *= i1; }

  if (FINAL) {
    float4* o0 = (float4*)(out + ((size_t)b * N + n0 + q) * K + kh * 32);
    float4* o1 = (float4*)(out + ((size_t)b * N + n0 + q + 128) * K + kh * 32);
#pragma unroll
    for (int g = 0; g < 8; ++g) {
      o0[g] = make_float4(a0[4 * g], a0[4 * g + 1], a0[4 * g + 2], a0[4 * g + 3]);
      o1[g] = make_float4(a1[4 * g], a1[4 * g + 1], a1[4 * g + 2], a1[4 * g + 3]);
    }
    return;
  }

  // ---- phase 2 ----
  __syncthreads();  // everyone done reading sm as m
  {                 // write z-tile [nloc][k] into sm
    float4* z0 = (float4*)&sm[q * K + kh * 32];
    float4* z1 = (float4*)&sm[(q + 128) * K + kh * 32];
#pragma unroll
    for (int g = 0; g < 8; ++g) {
      z0[g] = make_float4(a0[4 * g], a0[4 * g + 1], a0[4 * g + 2], a0[4 * g + 3]);
      z1[g] = make_float4(a1[4 * g], a1[4 * g + 1], a1[4 * g + 2], a1[4 * g + 3]);
    }
  }
  __syncthreads();

  {  // S[b,k] += sum over this block's n of z; thread = (k, n-quarter)
    const int k = tid & 63, qt = tid >> 6;
    float s = 0.f;
#pragma unroll
    for (int nn = 0; nn < 64; ++nn) s += sm[(qt * 64 + nn) * K + k];
    atomicAdd(&S[b * K + k], s);
  }

  // partial m'[c,k] = sum_{nn} x[c, n0+nn] * z[nn, k]; c in {q, q+128}
  float b0[32], b1[32];
#pragma unroll
  for (int i = 0; i < 32; ++i) { b0[i] = 0.f; b1[i] = 0.f; }

  const float4* xr0 = (const float4*)(x + ((size_t)b * C + q) * N + n0);
  const float4* xr1 = (const float4*)(x + ((size_t)b * C + q + 128) * N + n0);
  for (int t = 0; t < 64; ++t) {  // 4 n's per iter
    float4 w0 = xr0[t], w1 = xr1[t];
#pragma unroll
    for (int d = 0; d < 4; ++d) {
      const int nn = t * 4 + d;
      const float xv0 = d == 0 ? w0.x : d == 1 ? w0.y : d == 2 ? w0.z : w0.w;
      const float xv1 = d == 0 ? w1.x : d == 1 ? w1.y : d == 2 ? w1.z : w1.w;
#pragma unroll
      for (int j = 0; j < 8; ++j) {
        float4 zv = sm4[nn * 16 + kh * 8 + j];  // broadcast
        b0[4 * j + 0] += xv0 * zv.x; b0[4 * j + 1] += xv0 * zv.y;
        b0[4 * j + 2] += xv0 * zv.z; b0[4 * j + 3] += xv0 * zv.w;
        b1[4 * j + 0] += xv1 * zv.x; b1[4 * j + 1] += xv1 * zv.y;
        b1[4 * j + 2] += xv1 * zv.z; b1[4 * j + 3] += xv1 * zv.w;
      }
    }
  }

  float* mt0 = mt + ((size_t)b * C + q) * K + kh * 32;
  float* mt1 = mt + ((size_t)b * C + q + 128) * K + kh * 32;
#pragma unroll
  for (int i = 0; i < 32; ++i) {
    atomicAdd(&mt0[i], b0[i]);
    atomicAdd(&mt1[i], b1[i]);
  }
}

// m[b,c,k] = l2norm_c( mt[b,:,k] * l1scale[k] );  l1scale = 1/(EPS + S[b,k])
__global__ __launch_bounds__(64) void kl2_kernel(const float* __restrict__ mt,
                                                 const float* __restrict__ S,
                                                 float* __restrict__ m) {
  const int k = blockIdx.x, b = blockIdx.y, lane = threadIdx.x;
  const float s = 1.0f / (EPS + S[b * K + k]);
  float v[4];
  float ss = 0.f;
#pragma unroll
  for (int i = 0; i < 4; ++i) {
    v[i] = mt[((size_t)b * C + lane + 64 * i) * K + k] * s;
    ss += v[i] * v[i];
  }
#pragma unroll
  for (int off = 32; off >= 1; off >>= 1) ss += __shfl_xor(ss, off);
  const float inv = 1.0f / (EPS + sqrtf(ss));
#pragma unroll
  for (int i = 0; i < 4; ++i)
    m[((size_t)b * C + lane + 64 * i) * K + k] = v[i] * inv;
}

// init: m[b,c,k] = mu[c,k] (fp32 broadcast over b)
__global__ __launch_bounds__(256) void kinit_kernel(
    const float* __restrict__ mu, float* __restrict__ m) {
  const int idx = blockIdx.x * 256 + threadIdx.x;
  m[idx] = mu[idx & (C * K - 1)];
}

__global__ __launch_bounds__(256) void kzero_kernel(float* __restrict__ p, int ntot) {
  const int i = blockIdx.x * 256 + threadIdx.x;
  if (i < ntot) p[i] = 0.f;
}

extern "C" void kernel_launch(void* const* d_in, const int* in_sizes, int n_in,
                              void* d_out, int out_size, void* d_ws,
                              size_t ws_size, hipStream_t stream) {
  const float* x = (const float*)d_in[0];   // fp32 [B][C][N]
  const float* mu = (const float*)d_in[1];  // fp32 [1][C][K]
  float* out = (float*)d_out;               // fp32 [B][N][K]

  // ws layout (fp32): m[B*C*K] | mt[B*C*K] | S[B*K]  (~2.01 MB total)
  float* m = (float*)d_ws;
  float* mt = m + (size_t)B * C * K;
  float* S = mt + (size_t)B * C * K;
  const int nz = B * C * K + B * K;  // mt + S contiguous

  kinit_kernel<<<B * C * K / 256, 256, 0, stream>>>(mu, m);
  for (int step = 0; step < 3; ++step) {
    kzero_kernel<<<(nz + 255) / 256, 256, 0, stream>>>(mt, nz);
    kstep_kernel<false><<<dim3(N / 256, B), 256, 0, stream>>>(x, m, mt, S, nullptr);
    kl2_kernel<<<dim3(K, B), 64, 0, stream>>>(mt, S, m);
  }
  kstep_kernel<true><<<dim3(N / 256, B), 256, 0, stream>>>(x, m, nullptr, nullptr, out);
}